// Round 4
// baseline (26.151 us; speedup 1.0000x reference)
//
#include <hip/hip_runtime.h>

// z[i] = w * ( b * sum_t a^(T-1-t) x[i,t] + c * (1-a^T)/(1-a) ) + e
// T = 8192, B = 4096, x row-major [B][T], fp32.
// Two 64-lane waves per row; 512-thread block = 4 rows; grid = 1024.
// 8192 waves total = 32 waves/CU (full occupancy).

constexpr int T_LEN = 8192;
constexpr int BLOCK = 512;                     // 8 waves
constexpr int ROWS_PER_BLOCK = 4;              // 2 waves per row
constexpr int HALF = T_LEN / 2;                // 4096 elements per wave
constexpr int CHUNKS = HALF / (64 * 4);        // 16 float4 chunks per lane

typedef float vfloat4 __attribute__((ext_vector_type(4)));

__global__ __launch_bounds__(BLOCK) void recur_row_kernel(
    const float* __restrict__ x,
    const float* __restrict__ pa, const float* __restrict__ pb,
    const float* __restrict__ pc, const float* __restrict__ pw,
    const float* __restrict__ pe, float* __restrict__ out)
{
    const int wid   = threadIdx.x >> 6;        // wave id: 0..7
    const int lane  = threadIdx.x & 63;
    const int rloc  = wid >> 1;                // row within block: 0..3
    const int half  = wid & 1;                 // 0 = t[0..4095], 1 = t[4096..8191]
    const int row   = blockIdx.x * ROWS_PER_BLOCK + rloc;

    const float a = pa[0];
    const float b = pb[0];
    const float c = pc[0];
    const float w = pw[0];
    const float e = pe[0];

    // Double-precision powers (once per thread; negligible vs 16 KB stream).
    const double ad = (double)a;
    double a256d = ad;
    #pragma unroll
    for (int i = 0; i < 8; ++i) a256d *= a256d;     // a^256
    const float A256 = (float)a256d;

    // Per-lane combine weight: a^(4*(63-lane))
    int expn = 4 * (63 - lane);
    double wgt_d = 1.0, base = ad;
    while (expn) { if (expn & 1) wgt_d *= base; base *= base; expn >>= 1; }
    const float wgt = (float)wgt_d;

    // Stream this wave's half-row: lane reads float4 at u*64 + lane, u = 0..15.
    // p accumulates sum_{l=0}^{4095} a^(4095-l) * xh[l]  (after wgt factor).
    const vfloat4* xr = reinterpret_cast<const vfloat4*>(
        x + (size_t)row * T_LEN + (size_t)half * HALF);
    float p = 0.0f;
    #pragma unroll
    for (int u = 0; u < CHUNKS; ++u) {
        vfloat4 v = xr[u * 64 + lane];                     // plain load (L3-friendly)
        float q = ((v.x * a + v.y) * a + v.z) * a + v.w;   // Horner over 4 elems
        p = A256 * p + q;                                   // combine chunks
    }
    float part = wgt * p;

    // 64-lane wave reduce.
    #pragma unroll
    for (int off = 32; off > 0; off >>= 1)
        part += __shfl_down(part, off, 64);

    __shared__ float sred[8];
    if (lane == 0) sred[wid] = part;
    __syncthreads();

    // One thread per row combines the two half-sums and writes the output.
    if (threadIdx.x < ROWS_PER_BLOCK) {
        const int r = threadIdx.x;
        // a^4096 and S = (1 - a^8192)/(1 - a), in double.
        double a4096 = a256d * a256d;    // a^512
        a4096 *= a4096;                  // a^1024
        a4096 *= a4096;                  // a^2048
        a4096 *= a4096;                  // a^4096
        double a8192 = a4096 * a4096;
        double S = (1.0 - a8192) / (1.0 - ad);
        float D = (float)a4096 * sred[2 * r] + sred[2 * r + 1];
        out[blockIdx.x * ROWS_PER_BLOCK + r] = w * (b * D + c * (float)S) + e;
    }
}

extern "C" void kernel_launch(void* const* d_in, const int* in_sizes, int n_in,
                              void* d_out, int out_size, void* d_ws, size_t ws_size,
                              hipStream_t stream) {
    const float* x  = (const float*)d_in[0];
    const float* pa = (const float*)d_in[1];
    const float* pb = (const float*)d_in[2];
    const float* pc = (const float*)d_in[3];
    const float* pw = (const float*)d_in[4];
    const float* pe = (const float*)d_in[5];
    float* out = (float*)d_out;

    const int B = out_size;  // 4096 rows
    recur_row_kernel<<<dim3(B / ROWS_PER_BLOCK), dim3(BLOCK), 0, stream>>>(
        x, pa, pb, pc, pw, pe, out);
}

// Round 5
// 24.412 us; speedup vs baseline: 1.0712x; 1.0712x over previous
//
#include <hip/hip_runtime.h>

// z[i] = w * ( b * sum_t a^(T-1-t) x[i,t] + c * (1-a^T)/(1-a) ) + e
// T = 8192, B = 4096, x row-major [B][T], fp32.
// Two 64-lane waves per row; 512-thread block = 4 rows; grid = 1024.
// 8192 waves = 32 waves/CU (full occupancy) + nontemporal streaming loads.

constexpr int T_LEN = 8192;
constexpr int BLOCK = 512;                     // 8 waves
constexpr int ROWS_PER_BLOCK = 4;              // 2 waves per row
constexpr int HALF = T_LEN / 2;                // 4096 elements per wave
constexpr int CHUNKS = HALF / (64 * 4);        // 16 float4 chunks per lane

typedef float vfloat4 __attribute__((ext_vector_type(4)));

__global__ __launch_bounds__(BLOCK) void recur_row_kernel(
    const float* __restrict__ x,
    const float* __restrict__ pa, const float* __restrict__ pb,
    const float* __restrict__ pc, const float* __restrict__ pw,
    const float* __restrict__ pe, float* __restrict__ out)
{
    const int wid   = threadIdx.x >> 6;        // wave id: 0..7
    const int lane  = threadIdx.x & 63;
    const int rloc  = wid >> 1;                // row within block: 0..3
    const int half  = wid & 1;                 // 0 = t[0..4095], 1 = t[4096..8191]
    const int row   = blockIdx.x * ROWS_PER_BLOCK + rloc;

    const float a = pa[0];
    const float b = pb[0];
    const float c = pc[0];
    const float w = pw[0];
    const float e = pe[0];

    // Double-precision powers (once per thread; negligible vs 16 KB stream).
    const double ad = (double)a;
    double a256d = ad;
    #pragma unroll
    for (int i = 0; i < 8; ++i) a256d *= a256d;     // a^256
    const float A256 = (float)a256d;

    // Per-lane combine weight: a^(4*(63-lane))
    int expn = 4 * (63 - lane);
    double wgt_d = 1.0, base = ad;
    while (expn) { if (expn & 1) wgt_d *= base; base *= base; expn >>= 1; }
    const float wgt = (float)wgt_d;

    // Stream this wave's half-row: lane reads float4 at u*64 + lane, u = 0..15.
    const vfloat4* xr = reinterpret_cast<const vfloat4*>(
        x + (size_t)row * T_LEN + (size_t)half * HALF);
    float p = 0.0f;
    #pragma unroll
    for (int u = 0; u < CHUNKS; ++u) {
        vfloat4 v = __builtin_nontemporal_load(&xr[u * 64 + lane]);
        float q = ((v.x * a + v.y) * a + v.z) * a + v.w;   // Horner over 4 elems
        p = A256 * p + q;                                   // combine chunks
    }
    float part = wgt * p;

    // 64-lane wave reduce.
    #pragma unroll
    for (int off = 32; off > 0; off >>= 1)
        part += __shfl_down(part, off, 64);

    __shared__ float sred[8];
    if (lane == 0) sred[wid] = part;
    __syncthreads();

    // One thread per row combines the two half-sums and writes the output.
    if (threadIdx.x < ROWS_PER_BLOCK) {
        const int r = threadIdx.x;
        double a4096 = a256d * a256d;    // a^512
        a4096 *= a4096;                  // a^1024
        a4096 *= a4096;                  // a^2048
        a4096 *= a4096;                  // a^4096
        double a8192 = a4096 * a4096;
        double S = (1.0 - a8192) / (1.0 - ad);
        float D = (float)a4096 * sred[2 * r] + sred[2 * r + 1];
        out[blockIdx.x * ROWS_PER_BLOCK + r] = w * (b * D + c * (float)S) + e;
    }
}

extern "C" void kernel_launch(void* const* d_in, const int* in_sizes, int n_in,
                              void* d_out, int out_size, void* d_ws, size_t ws_size,
                              hipStream_t stream) {
    const float* x  = (const float*)d_in[0];
    const float* pa = (const float*)d_in[1];
    const float* pb = (const float*)d_in[2];
    const float* pc = (const float*)d_in[3];
    const float* pw = (const float*)d_in[4];
    const float* pe = (const float*)d_in[5];
    float* out = (float*)d_out;

    const int B = out_size;  // 4096 rows
    recur_row_kernel<<<dim3(B / ROWS_PER_BLOCK), dim3(BLOCK), 0, stream>>>(
        x, pa, pb, pc, pw, pe, out);
}

// Round 6
// 24.223 us; speedup vs baseline: 1.0796x; 1.0078x over previous
//
#include <hip/hip_runtime.h>

// z[i] = w * ( b * sum_t a^(T-1-t) x[i,t] + c * (1-a^T)/(1-a) ) + e
// T = 8192, B = 4096, x row-major [B][T], fp32.
// Two 64-lane waves per row; 512-thread block = 4 rows; grid = 1024.
// Diagnostic variant: 4 independent accumulator chains (break vmcnt serialization).

constexpr int T_LEN = 8192;
constexpr int BLOCK = 512;                     // 8 waves
constexpr int ROWS_PER_BLOCK = 4;              // 2 waves per row
constexpr int HALF = T_LEN / 2;                // 4096 elements per wave
constexpr int CHUNKS = HALF / (64 * 4);        // 16 float4 chunks per lane

typedef float vfloat4 __attribute__((ext_vector_type(4)));

__global__ __launch_bounds__(BLOCK) void recur_row_kernel(
    const float* __restrict__ x,
    const float* __restrict__ pa, const float* __restrict__ pb,
    const float* __restrict__ pc, const float* __restrict__ pw,
    const float* __restrict__ pe, float* __restrict__ out)
{
    const int wid   = threadIdx.x >> 6;        // wave id: 0..7
    const int lane  = threadIdx.x & 63;
    const int rloc  = wid >> 1;                // row within block: 0..3
    const int half  = wid & 1;                 // 0 = t[0..4095], 1 = t[4096..8191]
    const int row   = blockIdx.x * ROWS_PER_BLOCK + rloc;

    const float a = pa[0];
    const float b = pb[0];
    const float c = pc[0];
    const float w = pw[0];
    const float e = pe[0];

    // Double-precision powers (once per thread).
    const double ad = (double)a;
    double a256d = ad;
    #pragma unroll
    for (int i = 0; i < 8; ++i) a256d *= a256d;     // a^256
    const float A256 = (float)a256d;
    const double a1024d = ((a256d * a256d) * (a256d * a256d));  // a^1024
    const float A1024 = (float)a1024d;

    // Per-lane combine weight: a^(4*(63-lane))
    int expn = 4 * (63 - lane);
    double wgt_d = 1.0, base = ad;
    while (expn) { if (expn & 1) wgt_d *= base; base *= base; expn >>= 1; }
    const float wgt = (float)wgt_d;

    // Stream this wave's half-row with 4 INDEPENDENT accumulator chains.
    // Chain k handles chunks u = 4j+k (j=0..3):  pk = A1024*pk + q_{4j+k}.
    // Recombine: P = ((p0*A256 + p1)*A256 + p2)*A256 + p3, which restores
    // weight a^{256*(15-u)} per chunk exactly.
    const vfloat4* xr = reinterpret_cast<const vfloat4*>(
        x + (size_t)row * T_LEN + (size_t)half * HALF);
    float p0 = 0.f, p1 = 0.f, p2 = 0.f, p3 = 0.f;
    #pragma unroll
    for (int j = 0; j < 4; ++j) {
        vfloat4 v0 = __builtin_nontemporal_load(&xr[(4 * j + 0) * 64 + lane]);
        vfloat4 v1 = __builtin_nontemporal_load(&xr[(4 * j + 1) * 64 + lane]);
        vfloat4 v2 = __builtin_nontemporal_load(&xr[(4 * j + 2) * 64 + lane]);
        vfloat4 v3 = __builtin_nontemporal_load(&xr[(4 * j + 3) * 64 + lane]);
        float q0 = ((v0.x * a + v0.y) * a + v0.z) * a + v0.w;
        float q1 = ((v1.x * a + v1.y) * a + v1.z) * a + v1.w;
        float q2 = ((v2.x * a + v2.y) * a + v2.z) * a + v2.w;
        float q3 = ((v3.x * a + v3.y) * a + v3.z) * a + v3.w;
        p0 = A1024 * p0 + q0;
        p1 = A1024 * p1 + q1;
        p2 = A1024 * p2 + q2;
        p3 = A1024 * p3 + q3;
    }
    float P = ((p0 * A256 + p1) * A256 + p2) * A256 + p3;
    float part = wgt * P;

    // 64-lane wave reduce.
    #pragma unroll
    for (int off = 32; off > 0; off >>= 1)
        part += __shfl_down(part, off, 64);

    __shared__ float sred[8];
    if (lane == 0) sred[wid] = part;
    __syncthreads();

    // One thread per row combines the two half-sums and writes the output.
    if (threadIdx.x < ROWS_PER_BLOCK) {
        const int r = threadIdx.x;
        double a4096 = a1024d * a1024d;  // a^2048
        a4096 *= a4096;                  // a^4096
        double a8192 = a4096 * a4096;
        double S = (1.0 - a8192) / (1.0 - ad);
        float D = (float)a4096 * sred[2 * r] + sred[2 * r + 1];
        out[blockIdx.x * ROWS_PER_BLOCK + r] = w * (b * D + c * (float)S) + e;
    }
}

extern "C" void kernel_launch(void* const* d_in, const int* in_sizes, int n_in,
                              void* d_out, int out_size, void* d_ws, size_t ws_size,
                              hipStream_t stream) {
    const float* x  = (const float*)d_in[0];
    const float* pa = (const float*)d_in[1];
    const float* pb = (const float*)d_in[2];
    const float* pc = (const float*)d_in[3];
    const float* pw = (const float*)d_in[4];
    const float* pe = (const float*)d_in[5];
    float* out = (float*)d_out;

    const int B = out_size;  // 4096 rows
    recur_row_kernel<<<dim3(B / ROWS_PER_BLOCK), dim3(BLOCK), 0, stream>>>(
        x, pa, pb, pc, pw, pe, out);
}